// Round 8
// baseline (28.705 us; speedup 1.0000x reference)
//
#include <hip/hip_runtime.h>

#define NCLS 64
#define TDIM 512
#define PD   8   // prefetch depth (general path)

typedef _Float16 h2 __attribute__((ext_vector_type(2)));

#if __has_builtin(__builtin_amdgcn_fdot2)
#define FDOT2(a, b, c) __builtin_amdgcn_fdot2((a), (b), (c), false)
#else
static __device__ __forceinline__ float FDOT2(h2 a, h2 b, float c) {
    return fmaf((float)a.x, (float)b.x, fmaf((float)a.y, (float)b.y, c));
}
#endif

#define BC_H2(x) __builtin_bit_cast(h2, (x))
#define LN64 4.1588830833596715f

// Single kernel, two paths decided by a block-uniform check of the transition
// matrix:
//  FAST (uniform T == c): the CRF forward recurrence separates —
//    L_t = LSE_i(lg_t,i/64) independent per t,
//    partition(len) = R_{len-1} + 64*(len*c + ln64 + sum_{u<=len-2} L_u),
//    R_t = sum_i lg_t,i/64,
//    gold = lg[0,tg0] + 64c + len*c + sum_{m=1..len} lg[m, tg_m]
//  GENERAL: round-4 serial exp-space recurrence (wave 0 only).
__global__ __launch_bounds__(256) void crf_kernel(
    const float* __restrict__ logits,   // [N, T, C] f32
    const int*   __restrict__ lengths,  // [N] i32
    const int*   __restrict__ tags,     // [N, T] i32
    const float* __restrict__ trans,    // [C, C] f32
    float* __restrict__ out, int N)
{
    const int n = blockIdx.x;
    if (n >= N) return;
    const int tid = threadIdx.x;

    __shared__ float sL[TDIM];
    __shared__ float sRed[4];
    __shared__ float sRlast;
    __shared__ int   s_flag;
    __shared__ __align__(16) _Float16 fh_lds[NCLS];

    // ---- uniformity check: all 4096 words bit-equal to trans[0] ----
    const unsigned c0b = __builtin_bit_cast(unsigned, trans[0]);
    {
        const float4* tv = reinterpret_cast<const float4*>(trans);
        int ok = 1;
        #pragma unroll
        for (int q = 0; q < 4; ++q) {
            const float4 v = tv[tid * 4 + q];
            ok &= (__builtin_bit_cast(unsigned, v.x) == c0b);
            ok &= (__builtin_bit_cast(unsigned, v.y) == c0b);
            ok &= (__builtin_bit_cast(unsigned, v.z) == c0b);
            ok &= (__builtin_bit_cast(unsigned, v.w) == c0b);
        }
        if (tid == 0) s_flag = 1;
        __syncthreads();
        if (!ok) atomicAnd(&s_flag, 0);
        __syncthreads();
    }

    const int len = lengths[n];               // in [1, T-1]
    const float* lg = logits + (size_t)n * TDIM * NCLS;
    const int*   tg = tags   + (size_t)n * TDIM;
    const float I64 = 1.0f / 64.0f;

    if (s_flag) {
        // =============== FAST PATH (all 256 threads) ===============
        const float c   = trans[0];
        const int   sub = tid & 15;    // position within row (float4 index)
        const int   rg  = tid >> 4;    // row group: 16 rows in flight per pass

        // rows 0..len-1: coalesced (wave = 4 contiguous rows = 1 KB/instr).
        const float4* rp = reinterpret_cast<const float4*>(lg);
        for (int row = rg; row < len; row += 16) {
            const float4 v = rp[row * 16 + sub];
            float mx = fmaxf(fmaxf(v.x, v.y), fmaxf(v.z, v.w));
            #pragma unroll
            for (int o = 8; o; o >>= 1) mx = fmaxf(mx, __shfl_xor(mx, o));
            float es = __expf((v.x - mx) * I64) + __expf((v.y - mx) * I64)
                     + __expf((v.z - mx) * I64) + __expf((v.w - mx) * I64);
            #pragma unroll
            for (int o = 8; o; o >>= 1) es += __shfl_xor(es, o);
            if (sub == 0) sL[row] = mx * I64 + __logf(es);   // L_row
            if (row == len - 1) {
                float rs = (v.x + v.y) + (v.z + v.w);
                #pragma unroll
                for (int o = 8; o; o >>= 1) rs += __shfl_xor(rs, o);
                if (sub == 0) sRlast = rs * I64;             // R_{len-1}
            }
        }

        // gold-score gather partials (m = 1..len), wave-level reduce
        float g = 0.f;
        for (int m = tid + 1; m <= len; m += 256) {
            g += lg[(size_t)m * NCLS + tg[m]];
        }
        #pragma unroll
        for (int o = 32; o; o >>= 1) g += __shfl_xor(g, o);
        if ((tid & 63) == 0) sRed[tid >> 6] = g;
        __syncthreads();                 // publishes sL / sRlast / sRed

        if (tid < 64) {
            float S = 0.f;
            for (int u = tid; u < len - 1; u += 64) S += sL[u];
            #pragma unroll
            for (int o = 32; o; o >>= 1) S += __shfl_xor(S, o);
            if (tid == 0) {
                const int   t0   = tg[0];
                const float gall = (sRed[0] + sRed[1]) + (sRed[2] + sRed[3]);
                const float part = sRlast + 64.0f * ((float)len * c + LN64 + S);
                const float gold = lg[t0] + 64.0f * c + (float)len * c + gall;
                out[n] = part - gold;
            }
        }
        return;
    }

    // =============== GENERAL PATH (wave 0 only) ===============
    if (tid >= 64) return;
    const int lane = tid;               // class index i, 0..63
    const float INV_C = 1.0f / (float)NCLS;

    // preload tags (gold-score tail)
    int tr8[PD];
    #pragma unroll
    for (int k = 0; k < PD; ++k) tr8[k] = tg[lane + NCLS * k];

    // transition row `lane`: max + row-sum + exp-space f16 pack
    float trow[NCLS];
    #pragma unroll
    for (int q = 0; q < 16; ++q) {
        const float4 v = *reinterpret_cast<const float4*>(&trans[lane * NCLS + q * 4]);
        trow[4*q] = v.x; trow[4*q+1] = v.y; trow[4*q+2] = v.z; trow[4*q+3] = v.w;
    }
    float tmax = -3.0e38f, tsum = 0.f;
    #pragma unroll
    for (int j = 0; j < NCLS; ++j) { tmax = fmaxf(tmax, trow[j]); tsum += trow[j]; }
    float mT = tmax;
    #pragma unroll
    for (int o = 32; o; o >>= 1) mT = fmaxf(mT, __shfl_xor(mT, o));
    h2 tp[NCLS / 2];
    #pragma unroll
    for (int j = 0; j < NCLS; j += 2) {
        const float e0 = __expf(trow[j]     - mT) * 0.015625f;
        const float e1 = __expf(trow[j + 1] - mT) * 0.015625f;
        h2 p; p.x = (_Float16)e0; p.y = (_Float16)e1;
        tp[j >> 1] = p;
    }

    const int   t0 = __shfl(tr8[0], 0);          // tags[0]
    const float rs = __shfl(tsum, t0);           // row-sum of T at row tags[0]
    const float first = lg[t0] + rs;

    // exp-space recurrence:
    // alpha_i(t) = B_t + ln f_i, B_t = t*(mT+ln64) + B_renorm (uniform, analytic)
    // f'_i = (sum_j expT[i,j] * f_j) * p_i,  p_i = exp(logit_t,i / 64)
    float f = 1.0f;
    float B = 0.0f;

    float lgr[PD];
    #pragma unroll
    for (int k = 0; k < PD; ++k) lgr[k] = lg[(size_t)k * NCLS + lane];

    const int nblk = len >> 3;
    const int tail = len & 7;

    #define CRF_STEP(PVAL)                                                     \
    {                                                                          \
        fh_lds[lane] = (_Float16)f;                                            \
        float d0 = 0.f, d1 = 0.f, d2 = 0.f, d3 = 0.f;                          \
        _Pragma("unroll")                                                      \
        for (int j = 0; j < NCLS; j += 16) {                                   \
            const float4 a  = *reinterpret_cast<const float4*>(&fh_lds[j]);    \
            const float4 b4 = *reinterpret_cast<const float4*>(&fh_lds[j+8]);  \
            d0 = FDOT2(tp[(j >> 1) + 0], BC_H2(a.x),  d0);                     \
            d1 = FDOT2(tp[(j >> 1) + 1], BC_H2(a.y),  d1);                     \
            d2 = FDOT2(tp[(j >> 1) + 2], BC_H2(a.z),  d2);                     \
            d3 = FDOT2(tp[(j >> 1) + 3], BC_H2(a.w),  d3);                     \
            d0 = FDOT2(tp[(j >> 1) + 4], BC_H2(b4.x), d0);                     \
            d1 = FDOT2(tp[(j >> 1) + 5], BC_H2(b4.y), d1);                     \
            d2 = FDOT2(tp[(j >> 1) + 6], BC_H2(b4.z), d2);                     \
            d3 = FDOT2(tp[(j >> 1) + 7], BC_H2(b4.w), d3);                     \
        }                                                                      \
        const float dot = (d0 + d1) + (d2 + d3);                               \
        f = dot * (PVAL);                                                      \
    }

    int t = 0;
    for (int b = 0; b < nblk; ++b) {
        #pragma unroll
        for (int k = 0; k < PD; ++k) {
            const float p = __expf(lgr[k] * INV_C);      // off critical path
            int nidx = t + k + PD; nidx = (nidx > TDIM - 1) ? (TDIM - 1) : nidx;
            lgr[k] = lg[(size_t)nidx * NCLS + lane];     // lands 8 steps out
            CRF_STEP(p);
        }
        t += PD;
        if ((b & 7) == 7) {            // periodic renorm
            float r = __builtin_bit_cast(float,
                          __builtin_amdgcn_readfirstlane(__builtin_bit_cast(int, f)));
            r = fmaxf(r, 1e-30f);
            f *= __builtin_amdgcn_rcpf(r);
            B += __logf(r);
        }
    }

    #pragma unroll
    for (int k = 0; k < PD - 1; ++k) {
        if (k < tail) {
            const float p = __expf(lgr[k] * INV_C);
            CRF_STEP(p);
        }
    }
    #undef CRF_STEP

    // gold score: tags in registers; all gathers issue at once
    float g = 0.f;
    #pragma unroll
    for (int k = 0; k < PD; ++k) {
        const int m = 1 + lane + NCLS * k;
        if (m <= len) {
            const int rot  = __shfl(tr8[k], (lane + 1) & 63);        // tg[m], lane<63
            const int wrap = __shfl(tr8[(k + 1) & (PD - 1)], 0);     // tg[m], lane==63
            const int tm = (lane == 63) ? wrap : rot;
            const int tp_ = tr8[k];                                   // tg[m-1]
            g += trans[tm * NCLS + tp_] + lg[(size_t)m * NCLS + tm];
        }
    }

    float v = __logf(f) - g;
    #pragma unroll
    for (int o = 32; o; o >>= 1) v += __shfl_xor(v, o);

    if (lane == 0) {
        const float Bt = (float)len * (mT + LN64) + B;
        out[n] = 64.0f * Bt + v - first;
    }
}

extern "C" void kernel_launch(void* const* d_in, const int* in_sizes, int n_in,
                              void* d_out, int out_size, void* d_ws, size_t ws_size,
                              hipStream_t stream) {
    const float* logits  = (const float*)d_in[0];
    const int*   lengths = (const int*)  d_in[1];
    const int*   tags    = (const int*)  d_in[2];
    const float* trans   = (const float*)d_in[3];
    float* out = (float*)d_out;
    const int N = in_sizes[1];   // 512

    crf_kernel<<<N, 256, 0, stream>>>(logits, lengths, tags, trans, out, N);
}

// Round 9
// 18.687 us; speedup vs baseline: 1.5361x; 1.5361x over previous
//
#include <hip/hip_runtime.h>

#define NCLS 64
#define TDIM 512
#define PD   8   // prefetch depth (general path)

typedef _Float16 h2 __attribute__((ext_vector_type(2)));

#if __has_builtin(__builtin_amdgcn_fdot2)
#define FDOT2(a, b, c) __builtin_amdgcn_fdot2((a), (b), (c), false)
#else
static __device__ __forceinline__ float FDOT2(h2 a, h2 b, float c) {
    return fmaf((float)a.x, (float)b.x, fmaf((float)a.y, (float)b.y, c));
}
#endif

#define BC_H2(x) __builtin_bit_cast(h2, (x))
#define LN64 4.1588830833596715f

// Single kernel, two paths decided by a block-wide vote on the transition
// matrix:
//  FAST (uniform T == c): the CRF forward recurrence separates —
//    L_t = LSE_i(lg_t,i/64) independent per t,
//    partition(len) = R_{len-1} + 64*(len*c + ln64 + sum_{u<=len-2} L_u),
//    R_t = sum_i lg_t,i/64,
//    gold = lg[0,tg0] + 64c + len*c + sum_{m=1..len} lg[m, tg_m]
//    -> one thread per row, one pass, everything folds into ONE block reduce.
//  GENERAL: round-4 serial exp-space recurrence (wave 0 only).
__global__ __launch_bounds__(512) void crf_kernel(
    const float* __restrict__ logits,   // [N, T, C] f32
    const int*   __restrict__ lengths,  // [N] i32
    const int*   __restrict__ tags,     // [N, T] i32
    const float* __restrict__ trans,    // [C, C] f32
    float* __restrict__ out, int N)
{
    const int n = blockIdx.x;
    if (n >= N) return;
    const int tid = threadIdx.x;

    __shared__ float sRed[8];
    __shared__ __align__(16) _Float16 fh_lds[NCLS];

    // ---- uniformity vote: 4096 words, 8 per thread, single HW-vote barrier ----
    int ok;
    {
        const unsigned c0b = __builtin_bit_cast(unsigned, trans[0]);
        const float4 a = reinterpret_cast<const float4*>(trans)[tid * 2];
        const float4 b = reinterpret_cast<const float4*>(trans)[tid * 2 + 1];
        ok  = (__builtin_bit_cast(unsigned, a.x) == c0b);
        ok &= (__builtin_bit_cast(unsigned, a.y) == c0b);
        ok &= (__builtin_bit_cast(unsigned, a.z) == c0b);
        ok &= (__builtin_bit_cast(unsigned, a.w) == c0b);
        ok &= (__builtin_bit_cast(unsigned, b.x) == c0b);
        ok &= (__builtin_bit_cast(unsigned, b.y) == c0b);
        ok &= (__builtin_bit_cast(unsigned, b.z) == c0b);
        ok &= (__builtin_bit_cast(unsigned, b.w) == c0b);
    }
    const int uni = __syncthreads_and(ok);

    const int len = lengths[n];               // in [1, T-1]
    const float* lg = logits + (size_t)n * TDIM * NCLS;
    const int*   tg = tags   + (size_t)n * TDIM;
    const float I64 = 1.0f / 64.0f;

    if (uni) {
        // =============== FAST PATH: thread tid owns row tid ===============
        float contrib = 0.f;

        if (tid < len) {
            const float4* rp = reinterpret_cast<const float4*>(lg + (size_t)tid * NCLS);
            float4 vv[16];
            #pragma unroll
            for (int q = 0; q < 16; ++q) vv[q] = rp[q];   // 16 independent loads

            float mx = -3.0e38f;
            #pragma unroll
            for (int q = 0; q < 16; ++q)
                mx = fmaxf(mx, fmaxf(fmaxf(vv[q].x, vv[q].y), fmaxf(vv[q].z, vv[q].w)));
            float es = 0.f;
            #pragma unroll
            for (int q = 0; q < 16; ++q)
                es += __expf((vv[q].x - mx) * I64) + __expf((vv[q].y - mx) * I64)
                    + __expf((vv[q].z - mx) * I64) + __expf((vv[q].w - mx) * I64);

            if (tid <= len - 2)
                contrib += 64.0f * (mx * I64 + __logf(es));      // 64 * L_tid
            if (tid == len - 1) {
                float rs = 0.f;
                #pragma unroll
                for (int q = 0; q < 16; ++q) rs += (vv[q].x + vv[q].y) + (vv[q].z + vv[q].w);
                contrib += rs * I64;                             // R_{len-1}
            }
        }
        // gold gathers: row tid is L1-hot for tid<len; tid==len is one cold lane
        if (tid >= 1 && tid <= len) contrib -= lg[(size_t)tid * NCLS + tg[tid]];
        if (tid == 0)               contrib -= lg[tg[0]];

        // ---- one block-wide reduction (8 waves -> 8 partials -> lane 0) ----
        #pragma unroll
        for (int o = 32; o; o >>= 1) contrib += __shfl_xor(contrib, o);
        if ((tid & 63) == 0) sRed[tid >> 6] = contrib;
        __syncthreads();
        if (tid == 0) {
            float s = 0.f;
            #pragma unroll
            for (int w = 0; w < 8; ++w) s += sRed[w];
            const float c = trans[0];     // L1-hot
            out[n] = s + 64.0f * ((float)len * c + LN64) - 64.0f * c - (float)len * c;
        }
        return;
    }

    // =============== GENERAL PATH (wave 0 only) ===============
    if (tid >= 64) return;
    const int lane = tid;               // class index i, 0..63
    const float INV_C = 1.0f / (float)NCLS;

    // preload tags (gold-score tail)
    int tr8[PD];
    #pragma unroll
    for (int k = 0; k < PD; ++k) tr8[k] = tg[lane + NCLS * k];

    // transition row `lane`: max + row-sum + exp-space f16 pack
    float trow[NCLS];
    #pragma unroll
    for (int q = 0; q < 16; ++q) {
        const float4 v = *reinterpret_cast<const float4*>(&trans[lane * NCLS + q * 4]);
        trow[4*q] = v.x; trow[4*q+1] = v.y; trow[4*q+2] = v.z; trow[4*q+3] = v.w;
    }
    float tmax = -3.0e38f, tsum = 0.f;
    #pragma unroll
    for (int j = 0; j < NCLS; ++j) { tmax = fmaxf(tmax, trow[j]); tsum += trow[j]; }
    float mT = tmax;
    #pragma unroll
    for (int o = 32; o; o >>= 1) mT = fmaxf(mT, __shfl_xor(mT, o));
    h2 tp[NCLS / 2];
    #pragma unroll
    for (int j = 0; j < NCLS; j += 2) {
        const float e0 = __expf(trow[j]     - mT) * 0.015625f;
        const float e1 = __expf(trow[j + 1] - mT) * 0.015625f;
        h2 p; p.x = (_Float16)e0; p.y = (_Float16)e1;
        tp[j >> 1] = p;
    }

    const int   t0 = __shfl(tr8[0], 0);          // tags[0]
    const float rs = __shfl(tsum, t0);           // row-sum of T at row tags[0]
    const float first = lg[t0] + rs;

    // exp-space recurrence:
    // alpha_i(t) = B_t + ln f_i, B_t = t*(mT+ln64) + B_renorm (uniform, analytic)
    // f'_i = (sum_j expT[i,j] * f_j) * p_i,  p_i = exp(logit_t,i / 64)
    float f = 1.0f;
    float B = 0.0f;

    float lgr[PD];
    #pragma unroll
    for (int k = 0; k < PD; ++k) lgr[k] = lg[(size_t)k * NCLS + lane];

    const int nblk = len >> 3;
    const int tail = len & 7;

    #define CRF_STEP(PVAL)                                                     \
    {                                                                          \
        fh_lds[lane] = (_Float16)f;                                            \
        float d0 = 0.f, d1 = 0.f, d2 = 0.f, d3 = 0.f;                          \
        _Pragma("unroll")                                                      \
        for (int j = 0; j < NCLS; j += 16) {                                   \
            const float4 a  = *reinterpret_cast<const float4*>(&fh_lds[j]);    \
            const float4 b4 = *reinterpret_cast<const float4*>(&fh_lds[j+8]);  \
            d0 = FDOT2(tp[(j >> 1) + 0], BC_H2(a.x),  d0);                     \
            d1 = FDOT2(tp[(j >> 1) + 1], BC_H2(a.y),  d1);                     \
            d2 = FDOT2(tp[(j >> 1) + 2], BC_H2(a.z),  d2);                     \
            d3 = FDOT2(tp[(j >> 1) + 3], BC_H2(a.w),  d3);                     \
            d0 = FDOT2(tp[(j >> 1) + 4], BC_H2(b4.x), d0);                     \
            d1 = FDOT2(tp[(j >> 1) + 5], BC_H2(b4.y), d1);                     \
            d2 = FDOT2(tp[(j >> 1) + 6], BC_H2(b4.z), d2);                     \
            d3 = FDOT2(tp[(j >> 1) + 7], BC_H2(b4.w), d3);                     \
        }                                                                      \
        const float dot = (d0 + d1) + (d2 + d3);                               \
        f = dot * (PVAL);                                                      \
    }

    int t = 0;
    for (int b = 0; b < nblk; ++b) {
        #pragma unroll
        for (int k = 0; k < PD; ++k) {
            const float p = __expf(lgr[k] * INV_C);      // off critical path
            int nidx = t + k + PD; nidx = (nidx > TDIM - 1) ? (TDIM - 1) : nidx;
            lgr[k] = lg[(size_t)nidx * NCLS + lane];     // lands 8 steps out
            CRF_STEP(p);
        }
        t += PD;
        if ((b & 7) == 7) {            // periodic renorm
            float r = __builtin_bit_cast(float,
                          __builtin_amdgcn_readfirstlane(__builtin_bit_cast(int, f)));
            r = fmaxf(r, 1e-30f);
            f *= __builtin_amdgcn_rcpf(r);
            B += __logf(r);
        }
    }

    #pragma unroll
    for (int k = 0; k < PD - 1; ++k) {
        if (k < tail) {
            const float p = __expf(lgr[k] * INV_C);
            CRF_STEP(p);
        }
    }
    #undef CRF_STEP

    // gold score: tags in registers; all gathers issue at once
    float g = 0.f;
    #pragma unroll
    for (int k = 0; k < PD; ++k) {
        const int m = 1 + lane + NCLS * k;
        if (m <= len) {
            const int rot  = __shfl(tr8[k], (lane + 1) & 63);        // tg[m], lane<63
            const int wrap = __shfl(tr8[(k + 1) & (PD - 1)], 0);     // tg[m], lane==63
            const int tm = (lane == 63) ? wrap : rot;
            const int tp_ = tr8[k];                                   // tg[m-1]
            g += trans[tm * NCLS + tp_] + lg[(size_t)m * NCLS + tm];
        }
    }

    float v = __logf(f) - g;
    #pragma unroll
    for (int o = 32; o; o >>= 1) v += __shfl_xor(v, o);

    if (lane == 0) {
        const float Bt = (float)len * (mT + LN64) + B;
        out[n] = 64.0f * Bt + v - first;
    }
}

extern "C" void kernel_launch(void* const* d_in, const int* in_sizes, int n_in,
                              void* d_out, int out_size, void* d_ws, size_t ws_size,
                              hipStream_t stream) {
    const float* logits  = (const float*)d_in[0];
    const int*   lengths = (const int*)  d_in[1];
    const int*   tags    = (const int*)  d_in[2];
    const float* trans   = (const float*)d_in[3];
    float* out = (float*)d_out;
    const int N = in_sizes[1];   // 512

    crf_kernel<<<N, 512, 0, stream>>>(logits, lengths, tags, trans, out, N);
}